// Round 9
// baseline (159.186 us; speedup 1.0000x reference)
//
#include <hip/hip_runtime.h>

// MyHingeLoss: cosine hinge loss, N=32768, D=512, fp32. Floor ~21 us.
// R3: 56us atomic-serialized. R8: 50us, residency-INSENSITIVE, VALU 17%,
// HBM 17% -> latency/on-chip bound. Suspect: 56/72 VMEM per wave were
// redundant t5 re-reads; t5 can't stay L1-resident (32KB L1 vs ~512KB/CU
// of streaming rows) -> every wave hits L2's few t5 lines, serializing.
// R9 fix: t5 REGISTER-resident (64 lanes/row, lane owns {lane, lane+64}
// float4 positions -> 10 float4/lane loaded once/wave). 16 stream loads
// issued up-front for MLP. Trade: butterfly 6 steps x 32 chains.

constexpr int D   = 512;           // floats per row (128 float4)
constexpr int NC  = 5;             // NUM_COMPARE
constexpr float MARGIN_F = 0.1f;
constexpr float EPS_F    = 1e-6f;

__device__ __forceinline__ float dot4(const float4 a, const float4 b) {
  return a.x*b.x + a.y*b.y + a.z*b.z + a.w*b.w;
}

__global__ __launch_bounds__(256) void hinge_dots_kernel(
    const float* __restrict__ out, const float* __restrict__ tgt,
    float* __restrict__ wave_partial, int n)
{
  const int tid  = threadIdx.x;
  const int wid  = tid >> 6;
  const int lane = tid & 63;

  const float4* t5p = reinterpret_cast<const float4*>(tgt);

  // --- t5 into registers: t5r[j][h] = t5[j] float4 # (h*64 + lane). 10 VMEM.
  float4 t5r[NC][2];
  #pragma unroll
  for (int j = 0; j < NC; ++j) {
    t5r[j][0] = t5p[j * 128 + lane];
    t5r[j][1] = t5p[j * 128 + 64 + lane];
  }

  // --- tn5: in-lane square-sums, one 6-step butterfly for 5 values.
  float tsq[NC];
  #pragma unroll
  for (int j = 0; j < NC; ++j)
    tsq[j] = dot4(t5r[j][0], t5r[j][0]) + dot4(t5r[j][1], t5r[j][1]);
  #pragma unroll
  for (int off = 32; off; off >>= 1) {
    #pragma unroll
    for (int j = 0; j < NC; ++j) tsq[j] += __shfl_xor(tsq[j], off);
  }
  float tn5[NC];
  #pragma unroll
  for (int j = 0; j < NC; ++j) tn5[j] = sqrtf(tsq[j]);

  // --- 4 rows per wave; issue ALL 16 stream loads before consuming.
  const int gwave = blockIdx.x * 4 + wid;
  const int row0  = gwave * 4;
  float4 o[4][2], t[4][2];
  #pragma unroll
  for (int r = 0; r < 4; ++r) {
    const size_t rr = (size_t)min(row0 + r, n - 1) * 128;
    const float4* op = reinterpret_cast<const float4*>(out) + rr;
    const float4* tp = reinterpret_cast<const float4*>(tgt) + rr;
    o[r][0] = op[lane];  o[r][1] = op[64 + lane];
    t[r][0] = tp[lane];  t[r][1] = tp[64 + lane];
  }

  // --- in-lane partials: 8 per row (no memory ops here, t5 from regs).
  float s_ot[4], s_oo[4], s_tt[4], s5[4][NC];
  #pragma unroll
  for (int r = 0; r < 4; ++r) {
    s_ot[r] = dot4(o[r][0], t[r][0]) + dot4(o[r][1], t[r][1]);
    s_oo[r] = dot4(o[r][0], o[r][0]) + dot4(o[r][1], o[r][1]);
    s_tt[r] = dot4(t[r][0], t[r][0]) + dot4(t[r][1], t[r][1]);
    #pragma unroll
    for (int j = 0; j < NC; ++j)
      s5[r][j] = dot4(o[r][0], t5r[j][0]) + dot4(o[r][1], t5r[j][1]);
  }

  // --- batched butterfly: 32 independent chains x 6 steps.
  #pragma unroll
  for (int off = 32; off; off >>= 1) {
    #pragma unroll
    for (int r = 0; r < 4; ++r) {
      s_ot[r] += __shfl_xor(s_ot[r], off);
      s_oo[r] += __shfl_xor(s_oo[r], off);
      s_tt[r] += __shfl_xor(s_tt[r], off);
      #pragma unroll
      for (int j = 0; j < NC; ++j) s5[r][j] += __shfl_xor(s5[r][j], off);
    }
  }

  // --- epilogue (sums replicated in all lanes; lane 0 writes).
  if (lane == 0) {
    float acc = 0.f;
    #pragma unroll
    for (int r = 0; r < 4; ++r) {
      const int row = row0 + r;
      if (row < n) {
        const float on  = sqrtf(s_oo[r]);
        const float tn  = sqrtf(s_tt[r]);
        const float pos = s_ot[r] / fmaxf(on * tn, EPS_F);
        #pragma unroll
        for (int j = 0; j < NC; ++j) {
          const float S = s5[r][j] / fmaxf(on * tn5[j], EPS_F);
          const float h = fmaxf(0.f, MARGIN_F - pos + S);
          acc += (row == j) ? 0.f : h;
        }
      }
    }
    wave_partial[gwave] = acc;   // plain store, no atomic
  }
}

__global__ __launch_bounds__(256) void reduce_kernel(
    const float* __restrict__ part, float* __restrict__ result,
    int nw, float inv_count)
{
  float s = 0.f;
  for (int i = threadIdx.x; i < nw; i += 256) s += part[i];
  #pragma unroll
  for (int off = 32; off; off >>= 1) s += __shfl_xor(s, off);
  __shared__ float ws[4];
  if ((threadIdx.x & 63) == 0) ws[threadIdx.x >> 6] = s;
  __syncthreads();
  if (threadIdx.x == 0) result[0] = (ws[0] + ws[1] + ws[2] + ws[3]) * inv_count;
}

extern "C" void kernel_launch(void* const* d_in, const int* in_sizes, int n_in,
                              void* d_out, int out_size, void* d_ws, size_t ws_size,
                              hipStream_t stream) {
  const float* out = (const float*)d_in[0];
  const float* tgt = (const float*)d_in[1];
  float* result = (float*)d_out;
  float* partials = (float*)d_ws;

  const int n = in_sizes[0] / D;                       // 32768
  const int blocks = (n + 15) / 16;                    // 16 rows per block
  const int nwaves = blocks * 4;                       // 8192 partial slots
  const long long count = (long long)n * NC - (n < NC ? n : NC);
  const float inv_count = 1.0f / (float)count;

  hinge_dots_kernel<<<blocks, 256, 0, stream>>>(out, tgt, partials, n);
  reduce_kernel<<<1, 256, 0, stream>>>(partials, result, nwaves, inv_count);
}

// Round 16
// 148.642 us; speedup vs baseline: 1.0709x; 1.0709x over previous
//
#include <hip/hip_runtime.h>

// MyHingeLoss: cosine hinge loss, N=32768, D=512, fp32. Floor ~21 us.
// R3 56us / R8 50us / R9 53us: three structurally different kernels all
// pin ~50us, insensitive to atomics, VMEM count, AND L3 residency (warm
// FETCH=65KB dispatches == cold 65MB ones). Common factor: exact-fit
// co-resident grid (one generation) -> bulk-synchronous phases: all waves
// load-stall together, compute together; VALU 17-28% and mem 15% both
// idle. R10/R11: 4x oversubscription (one row per WAVE, 8192 blocks) so
// generations pipeline; DPP reduction on the VALU pipe (quad_perm xor1/
// xor2 + row_ror:4/8 — ctrl as TEMPLATE arg, builtin needs a literal);
// tn5 hoisted to a tiny pre-kernel.

constexpr int D   = 512;           // floats per row (128 float4)
constexpr int NC  = 5;             // NUM_COMPARE
constexpr float MARGIN_F = 0.1f;
constexpr float EPS_F    = 1e-6f;

__device__ __forceinline__ float dot4(const float4 a, const float4 b) {
  return a.x*b.x + a.y*b.y + a.z*b.z + a.w*b.w;
}

template <int CTRL>
__device__ __forceinline__ float dpp_add(float x) {
  const int y = __builtin_amdgcn_update_dpp(
      0, __float_as_int(x), CTRL, 0xF, 0xF, true);
  return x + __int_as_float(y);
}

// Full 64-lane sum, replicated in all lanes. 4 VALU-pipe DPP steps
// (xor1=quad_perm(1,0,3,2)=0xB1, xor2=quad_perm(2,3,0,1)=0x4E,
// row_ror:4=0x124, row_ror:8=0x128 -> 16-lane sums) + 2 cross-row shuffles.
__device__ __forceinline__ float red64(float x) {
  x = dpp_add<0xB1>(x);
  x = dpp_add<0x4E>(x);
  x = dpp_add<0x124>(x);
  x = dpp_add<0x128>(x);
  x += __shfl_xor(x, 16);
  x += __shfl_xor(x, 32);
  return x;
}

// Pre-kernel: tn5[j] = ||target[j]||, one wave per row, 1 block.
__global__ __launch_bounds__(320) void tn5_kernel(
    const float* __restrict__ tgt, float* __restrict__ tn5_out)
{
  const int w = threadIdx.x >> 6, lane = threadIdx.x & 63;
  const float4* tp = reinterpret_cast<const float4*>(tgt) + w * 128;
  const float4 a = tp[lane], b = tp[64 + lane];
  const float s = red64(dot4(a, a) + dot4(b, b));
  if (lane == 0) tn5_out[w] = sqrtf(s);
}

// Main: ONE ROW PER WAVE (64 lanes across D). 8192 blocks x 4 waves ->
// 32768 waves, ~4 generations deep -> cross-generation load/compute overlap.
__global__ __launch_bounds__(256) void hinge_kernel(
    const float* __restrict__ out, const float* __restrict__ tgt,
    const float* __restrict__ tn5g, float* __restrict__ partial, int n)
{
  const int tid  = threadIdx.x;
  const int wid  = tid >> 6;
  const int lane = tid & 63;
  const int row  = blockIdx.x * 4 + wid;
  __shared__ float bsum[4];

  float h = 0.f;
  if (row < n) {
    const float4* op = reinterpret_cast<const float4*>(out) + (size_t)row * 128;
    const float4* tp = reinterpret_cast<const float4*>(tgt) + (size_t)row * 128;
    const float4 o0 = op[lane], o1 = op[64 + lane];   // 2 coalesced 1KB loads
    const float4 t0 = tp[lane], t1 = tp[64 + lane];

    const float4* t5p = reinterpret_cast<const float4*>(tgt);  // rows 0..4, L2-hot
    float s_ot = dot4(o0, t0) + dot4(o1, t1);
    float s_oo = dot4(o0, o0) + dot4(o1, o1);
    float s_tt = dot4(t0, t0) + dot4(t1, t1);
    float s5[NC];
    #pragma unroll
    for (int j = 0; j < NC; ++j) {
      const float4 v0 = t5p[j * 128 + lane];
      const float4 v1 = t5p[j * 128 + 64 + lane];
      s5[j] = dot4(o0, v0) + dot4(o1, v1);
    }

    s_ot = red64(s_ot);
    s_oo = red64(s_oo);
    s_tt = red64(s_tt);
    #pragma unroll
    for (int j = 0; j < NC; ++j) s5[j] = red64(s5[j]);

    if (lane == 0) {
      const float on  = sqrtf(s_oo);
      const float tn  = sqrtf(s_tt);
      const float pos = s_ot / fmaxf(on * tn, EPS_F);
      #pragma unroll
      for (int j = 0; j < NC; ++j) {
        const float S = s5[j] / fmaxf(on * tn5g[j], EPS_F);
        const float hv = fmaxf(0.f, MARGIN_F - pos + S);
        h += (row == j) ? 0.f : hv;
      }
    }
  }
  if (lane == 0) bsum[wid] = h;
  __syncthreads();
  if (tid == 0) partial[blockIdx.x] = bsum[0] + bsum[1] + bsum[2] + bsum[3];
}

__global__ __launch_bounds__(256) void reduce_kernel(
    const float* __restrict__ part, float* __restrict__ result,
    int nw, float inv_count)
{
  float s = 0.f;
  for (int i = threadIdx.x; i < nw; i += 256) s += part[i];
  s = red64(s);
  __shared__ float ws[4];
  if ((threadIdx.x & 63) == 0) ws[threadIdx.x >> 6] = s;
  __syncthreads();
  if (threadIdx.x == 0) result[0] = (ws[0] + ws[1] + ws[2] + ws[3]) * inv_count;
}

extern "C" void kernel_launch(void* const* d_in, const int* in_sizes, int n_in,
                              void* d_out, int out_size, void* d_ws, size_t ws_size,
                              hipStream_t stream) {
  const float* out = (const float*)d_in[0];
  const float* tgt = (const float*)d_in[1];
  float* result   = (float*)d_out;
  float* partials = (float*)d_ws;            // [0 .. 8191]
  float* tn5_ws   = partials + 8192;         // [8192 .. 8196]

  const int n = in_sizes[0] / D;             // 32768
  const int blocks = (n + 3) / 4;            // 8192: one row per wave
  const long long count = (long long)n * NC - (n < NC ? n : NC);
  const float inv_count = 1.0f / (float)count;

  tn5_kernel<<<1, 320, 0, stream>>>(tgt, tn5_ws);
  hinge_kernel<<<blocks, 256, 0, stream>>>(out, tgt, tn5_ws, partials, n);
  reduce_kernel<<<1, 256, 0, stream>>>(partials, result, blocks, inv_count);
}